// Round 8
// baseline (53.212 us; speedup 1.0000x reference)
//
#include <hip/hip_runtime.h>
#include <hip/hip_bf16.h>
#include <math.h>

// InteractionBlock R8: split interact at the register-pressure boundary.
//  prep: cnt=0, gctr=0, pack W2 -> pre-swizzled bf16 MFMA B-fragments.
//  K_A : per-edge geometry/bessel-MLP (NO MFMA -> low VGPR -> high occupancy,
//        hides scattered-load latency). Ballot-compacts per block, claims a
//        global segment (1 atomicAdd per block), writes compact staging rows
//        hX[gpos][16] f32 + xsX[gpos][16] bf16 + ge[gpos]=e, Y -> data[e],
//        bucket-CSR (cnt/bucket) for the gather.
//  K_B : pure MFMA GEMM [ntotal,256](q = h (x) xs) x [256,48](W2 frags in
//        VGPRs, 96 regs -- isolated here so only this tiny kernel pays the
//        occupancy cost). Scatters v into data[e].
//  K_C : per-node gather over bucket entries, expand msg = v_l[h]*Y[m].
// R6/R7 lesson: (256,4) made the compiler dematerialize the B-frags; keeping
// MFMA+feature code fused capped phase A at 3 waves/SIMD (latency-bound).

typedef __attribute__((ext_vector_type(8))) short short8;
typedef __attribute__((ext_vector_type(4))) float f32x4;
typedef __attribute__((ext_vector_type(4))) unsigned short u16x4;

#define DSTRIDE 72   // ushorts per data row (144 B, 16B-aligned)
#define CAP 32       // bucket capacity (active in-degree ~Poisson(6.86), max ~22)

static __device__ __forceinline__ unsigned short f2bf(float f) {
  __hip_bfloat16 h = __float2bfloat16(f);   // RNE
  return __builtin_bit_cast(unsigned short, h);
}
static __device__ __forceinline__ float bf2f(unsigned short s) {
  unsigned u = ((unsigned)s) << 16;
  return __builtin_bit_cast(float, u);
}

// ---- prep: cnt=0 + gctr=0 + W2 -> bf16 B-fragments ----
// frag fi = s*3+t (s=k-step 0..7, t=n-tile 0..2); entry (fi,lane,j):
//   k_global = s*32 + (lane>>4)*8 + j, n = t*16 + (lane&15)
//   W2r[k][n] = W2[kk*768 + t*256 + c*16 + h], kk=k>>4, c=k&15, h=lane&15
__global__ __launch_bounds__(256)
void prep_kernel(const float* __restrict__ W2, unsigned short* __restrict__ w2f,
                 int* __restrict__ cnt, int* __restrict__ gctr, int N) {
  int gid = blockIdx.x * 256 + threadIdx.x;
  if (gid < N) cnt[gid] = 0;
  if (gid == 0) *gctr = 0;
  if (gid < 24 * 64) {
    int fi = gid >> 6, lane = gid & 63;
    int s = fi / 3, t = fi - 3 * s;
    int h = lane & 15, kq = lane >> 4;
    short8 pack;
    #pragma unroll
    for (int j = 0; j < 8; ++j) {
      int kg = s * 32 + kq * 8 + j;
      int kk = kg >> 4, c = kg & 15;
      pack[j] = (short)f2bf(W2[kk * 768 + t * 256 + c * 16 + h]);
    }
    *(short8*)&w2f[(size_t)gid * 8] = pack;
  }
}

// ---- K_A: per-edge features -> compact staging (high occupancy, no MFMA) ----
__global__ __launch_bounds__(256)
void featA_kernel(const float* __restrict__ xfeat,
                  const float* __restrict__ coords,
                  const int* __restrict__ eidx,
                  const float* __restrict__ W1g,
                  unsigned short* __restrict__ data,  // [E][72] bf16 (Y here)
                  int* __restrict__ cnt,              // [N] zeroed
                  int* __restrict__ bucket,           // [N][CAP]
                  float* __restrict__ hX,             // [E][16] f32 compact
                  unsigned short* __restrict__ xsX,   // [E][16] bf16 compact
                  int* __restrict__ ge,               // [E] compact -> edge id
                  int* __restrict__ gctr,
                  int E)
{
  __shared__ __align__(16) float W1s[256];
  __shared__ int wsum[4];
  __shared__ int sbase;

  const int tid  = threadIdx.x;
  const int lane = tid & 63, wid = tid >> 6;
  W1s[tid] = W1g[tid];

  const int e = blockIdx.x * 256 + tid;
  bool act = false;
  int src = 0, dst = 0;
  float rx = 0.f, ry = 0.f, rz = 0.f, d2 = 0.f;
  if (e < E) {
    src = eidx[e]; dst = eidx[E + e];
    rx = coords[3*src]   - coords[3*dst];
    ry = coords[3*src+1] - coords[3*dst+1];
    rz = coords[3*src+2] - coords[3*dst+2];
    d2 = rx*rx + ry*ry + rz*rz;
    act = (d2 > 0.0f) && (d2 < 36.0f);
  }
  unsigned long long bm = __ballot(act);
  int pfx = __popcll(bm & ((1ull << lane) - 1ull));
  if (lane == 0) wsum[wid] = __popcll(bm);
  __syncthreads();                                   // covers W1s + wsum
  int base = 0;
  #pragma unroll
  for (int w = 0; w < 4; ++w) base += (w < wid) ? wsum[w] : 0;
  const int total = wsum[0] + wsum[1] + wsum[2] + wsum[3];
  if (tid == 0) sbase = total ? atomicAdd(gctr, total) : 0;
  __syncthreads();

  if (!act) return;
  const int gpos = sbase + base + pfx;

  float dd  = sqrtf(d2);
  float inv = 1.0f / dd;
  float x = rx*inv, y = ry*inv, z = rz*inv;
  const float A1 = 0.48860251190291992f;  // sqrt(3)/sqrt(4pi)
  const float A2 = 1.09254843059207907f;  // sqrt(15)/sqrt(4pi)
  const float A3 = 0.63078313050504001f;  // sqrt(5)/sqrt(4pi)
  unsigned short* dr = data + (size_t)e * DSTRIDE;
  short8 ys;
  ys[0] = (short)f2bf(A1*x);   ys[1] = (short)f2bf(A1*y);  ys[2] = (short)f2bf(A1*z);
  ys[3] = (short)f2bf(A2*x*z); ys[4] = (short)f2bf(A2*x*y);
  ys[5] = (short)f2bf(A3*(y*y - 0.5f*(x*x + z*z)));
  ys[6] = (short)f2bf(A2*y*z); ys[7] = (short)f2bf(0.5f*A2*(z*z - x*x));
  *(short8*)&dr[64] = ys;
  int slot = atomicAdd(&cnt[dst], 1);
  if (slot < CAP) bucket[dst * CAP + slot] = e;

  // bessel -> hidden: h[j] = gain*silu( (eb@W1)[j]/4 )
  float theta = 0.52359877559829887f * dd;   // pi/6 * d
  float s1 = __sinf(theta), c1 = __cosf(theta);
  float snm = 0.0f, sn = s1;
  float4 hbv[4];
  #pragma unroll
  for (int q = 0; q < 4; ++q) hbv[q] = make_float4(0.f, 0.f, 0.f, 0.f);
  #pragma unroll
  for (int k = 0; k < 16; ++k) {
    #pragma unroll
    for (int q = 0; q < 4; ++q) {
      const float4 w = *((const float4*)&W1s[k*16 + q*4]);
      hbv[q].x = fmaf(sn, w.x, hbv[q].x);
      hbv[q].y = fmaf(sn, w.y, hbv[q].y);
      hbv[q].z = fmaf(sn, w.z, hbv[q].z);
      hbv[q].w = fmaf(sn, w.w, hbv[q].w);
    }
    float sp = 2.0f*c1*sn - snm;
    snm = sn; sn = sp;
  }
  const float scale1 = 2.30940107675850305f * inv * 0.25f;
  float* hrow = &hX[(size_t)gpos * 16];
  #pragma unroll
  for (int q = 0; q < 4; ++q) {
    float b[4] = {hbv[q].x, hbv[q].y, hbv[q].z, hbv[q].w};
    float4 o;
    float* op = (float*)&o;
    #pragma unroll
    for (int r = 0; r < 4; ++r) {
      float p = b[r] * scale1;
      op[r] = 1.679177f * p / (1.0f + __expf(-p));
    }
    *(float4*)&hrow[q*4] = o;
  }
  unsigned short* xrow = &xsX[(size_t)gpos * 16];
  #pragma unroll
  for (int cc = 0; cc < 2; ++cc) {
    float4 xa = *(const float4*)&xfeat[src*16 + cc*8];
    float4 xb = *(const float4*)&xfeat[src*16 + cc*8 + 4];
    u16x4 pa, pb;
    pa[0]=f2bf(xa.x); pa[1]=f2bf(xa.y); pa[2]=f2bf(xa.z); pa[3]=f2bf(xa.w);
    pb[0]=f2bf(xb.x); pb[1]=f2bf(xb.y); pb[2]=f2bf(xb.z); pb[3]=f2bf(xb.w);
    *(u16x4*)&xrow[cc*8]     = pa;
    *(u16x4*)&xrow[cc*8 + 4] = pb;
  }
  ge[gpos] = e;
}

// ---- K_B: pure MFMA GEMM over compacted groups ----
__global__ __launch_bounds__(256, 1)
void gemmB_kernel(const float* __restrict__ hX,
                  const unsigned short* __restrict__ xsX,
                  const int* __restrict__ ge,
                  const unsigned short* __restrict__ w2f,
                  unsigned short* __restrict__ data,
                  const int* __restrict__ gctr)
{
  const int tid  = threadIdx.x;
  const int lane = tid & 63, wid = tid >> 6;

  short8 bfr[8][3];
  #pragma unroll
  for (int s = 0; s < 8; ++s)
    #pragma unroll
    for (int t = 0; t < 3; ++t)
      bfr[s][t] = *(const short8*)&w2f[(size_t)((s*3 + t)*64 + lane) * 8];

  const int ntotal  = *gctr;
  const int ngroups = (ntotal + 15) >> 4;
  const int nwaves  = gridDim.x * 4;
  const int ma = lane & 15, kq = lane >> 4;
  const int hi = kq >> 1;
  const int c0 = (kq & 1) * 8;

  for (int g = blockIdx.x * 4 + wid; g < ngroups; g += nwaves) {
    const int cidx = g*16 + ma;          // staging row this lane feeds
    // 8 scattered f32 h-loads + one 16B xs load (finite even for tail rows;
    // NaN/garbage only contaminates MFMA output rows >= ntotal, never stored)
    float hk8[8];
    #pragma unroll
    for (int s = 0; s < 8; ++s) hk8[s] = hX[(size_t)cidx * 16 + 2*s + hi];
    short8 xv = *(const short8*)&xsX[(size_t)cidx * 16 + c0];
    float xsf[8];
    #pragma unroll
    for (int j = 0; j < 8; ++j) xsf[j] = bf2f((unsigned short)xv[j]);

    f32x4 acc0 = {0,0,0,0}, acc1 = {0,0,0,0}, acc2 = {0,0,0,0};
    #pragma unroll
    for (int s = 0; s < 8; ++s) {
      const float hk = hk8[s];
      short8 a;
      #pragma unroll
      for (int j = 0; j < 8; ++j) a[j] = (short)f2bf(hk * xsf[j]);
      acc0 = __builtin_amdgcn_mfma_f32_16x16x32_bf16(a, bfr[s][0], acc0, 0, 0, 0);
      acc1 = __builtin_amdgcn_mfma_f32_16x16x32_bf16(a, bfr[s][1], acc1, 0, 0, 0);
      acc2 = __builtin_amdgcn_mfma_f32_16x16x32_bf16(a, bfr[s][2], acc2, 0, 0, 0);
    }
    // D layout: row = kq*4 + r, col = lane&15  (m89-verified)
    const float sc = 0.00390625f;  // 1/256
    #pragma unroll
    for (int r = 0; r < 4; ++r) {
      const int cr = g*16 + kq*4 + r;
      if (cr < ntotal) {
        unsigned short* dr = data + (size_t)ge[cr] * DSTRIDE;
        u16x4 vv;
        vv[0] = f2bf(acc0[r] * sc);
        vv[1] = f2bf(acc1[r] * sc);
        vv[2] = f2bf(acc2[r] * sc);
        vv[3] = 0;
        *(u16x4*)&dr[ma * 4] = vv;
      }
    }
  }
}

// ---- K_C: gather (16 threads per node iterate its bucket) ----
__global__ __launch_bounds__(256)
void gather_kernel(const unsigned short* __restrict__ data,
                   const int* __restrict__ cnt,
                   const int* __restrict__ bucket,
                   float* __restrict__ out, int N)
{
  int gid = blockIdx.x * 256 + threadIdx.x;
  int node = gid >> 4, h = gid & 15;
  if (node >= N) return;

  float a0 = 0.f;
  float a10 = 0.f, a11 = 0.f, a12 = 0.f;
  float a20 = 0.f, a21 = 0.f, a22 = 0.f, a23 = 0.f, a24 = 0.f;

  int c = cnt[node];
  c = c < CAP ? c : CAP;
  const int* bk = &bucket[node * CAP];
  for (int i = 0; i < c; ++i) {
    const int p = bk[i];                      // broadcast across the 16 threads
    const unsigned short* dr = data + (size_t)p * DSTRIDE;
    u16x4 vv = *(const u16x4*)&dr[h * 4];
    short8 yv = *(const short8*)&dr[64];
    float v0 = bf2f(vv[0]), v1 = bf2f(vv[1]), v2 = bf2f(vv[2]);
    a0  += v0;
    a10 = fmaf(v1, bf2f((unsigned short)yv[0]), a10);
    a11 = fmaf(v1, bf2f((unsigned short)yv[1]), a11);
    a12 = fmaf(v1, bf2f((unsigned short)yv[2]), a12);
    a20 = fmaf(v2, bf2f((unsigned short)yv[3]), a20);
    a21 = fmaf(v2, bf2f((unsigned short)yv[4]), a21);
    a22 = fmaf(v2, bf2f((unsigned short)yv[5]), a22);
    a23 = fmaf(v2, bf2f((unsigned short)yv[6]), a23);
    a24 = fmaf(v2, bf2f((unsigned short)yv[7]), a24);
  }

  float* o = out + (size_t)node * 144;
  o[h] = a0 * 0.28209479177387814f;   // Y0 constant folded here
  o[16 + h*3 + 0] = a10;
  o[16 + h*3 + 1] = a11;
  o[16 + h*3 + 2] = a12;
  o[64 + h*5 + 0] = a20;
  o[64 + h*5 + 1] = a21;
  o[64 + h*5 + 2] = a22;
  o[64 + h*5 + 3] = a23;
  o[64 + h*5 + 4] = a24;
}

extern "C" void kernel_launch(void* const* d_in, const int* in_sizes, int n_in,
                              void* d_out, int out_size, void* d_ws, size_t ws_size,
                              hipStream_t stream) {
  const float* xfeat  = (const float*)d_in[0];
  const float* coords = (const float*)d_in[1];
  const int*   eidx   = (const int*)d_in[2];
  const float* W1     = (const float*)d_in[3];
  const float* W2     = (const float*)d_in[4];
  float* out = (float*)d_out;

  const int E = in_sizes[2] / 2;
  const int N = out_size / 144;

  // ws layout (16B-aligned chunks), total ~40.4 MB:
  // data[E][72]u16 | cnt[N] | bucket[N][CAP] | hX[E][16]f32 | xsX[E][16]u16 | ge[E] | w2f | gctr
  char* ws = (char*)d_ws;
  size_t off = 0;
  unsigned short* data = (unsigned short*)(ws + off); off += (size_t)E * DSTRIDE * 2;
  int* cnt    = (int*)(ws + off); off += (size_t)((N + 3) & ~3) * 4;
  int* bucket = (int*)(ws + off); off += (size_t)N * CAP * 4;
  float* hX   = (float*)(ws + off); off += (size_t)E * 16 * 4;
  unsigned short* xsX = (unsigned short*)(ws + off); off += (size_t)E * 16 * 2;
  int* ge     = (int*)(ws + off); off += (size_t)E * 4;
  unsigned short* w2f = (unsigned short*)(ws + off); off += 24576;
  int* gctr   = (int*)(ws + off);

  int pblk = (N + 255) / 256;
  if (pblk < 6) pblk = 6;
  prep_kernel<<<pblk, 256, 0, stream>>>(W2, w2f, cnt, gctr, N);
  featA_kernel<<<(E + 255) / 256, 256, 0, stream>>>(xfeat, coords, eidx, W1,
                                                    data, cnt, bucket, hX, xsX,
                                                    ge, gctr, E);
  gemmB_kernel<<<512, 256, 0, stream>>>(hX, xsX, ge, w2f, data, gctr);
  gather_kernel<<<(N * 16 + 255) / 256, 256, 0, stream>>>(data, cnt, bucket, out, N);
}

// Round 9
// 38.056 us; speedup vs baseline: 1.3983x; 1.3983x over previous
//
#include <hip/hip_runtime.h>
#include <hip/hip_bf16.h>
#include <math.h>

// InteractionBlock R9 = R4 (banked best, 37.4us) + early xfeat load issue.
// R5 lesson: in-kernel producer->consumer handoff needs agent-scope fences ->
//   L2 writeback storm on 8 non-coherent XCDs. Kernel boundary is the flush.
// R8 lesson: interact grid = 625 blocks = 2.44 blocks/CU -> ~10 waves/CU is
//   GRID-bound; raising the occupancy ceiling via kernel-splitting cannot help.
//  prep:   head[]=-1 + pack W2 -> pre-swizzled bf16 MFMA B-fragments.
//  K1:     per-edge geometry/bessel-MLP -> ballot compaction -> MFMA GEMM
//          [E,256](q = h (x) xs) x [256,48](W2 frags in VGPRs) -> factored bf16
//          message rows data[e] = { v[16][4], Y1..Y8 } + per-dst linked list.
//  K2:     per-node list gather, expand msg = v_l[h]*Y[m], write out once.

typedef __attribute__((ext_vector_type(8))) short short8;
typedef __attribute__((ext_vector_type(4))) float f32x4;
typedef __attribute__((ext_vector_type(4))) unsigned short u16x4;

#define DSTRIDE 72  // ushorts per data row (144 B, 16B-aligned)

static __device__ __forceinline__ unsigned short f2bf(float f) {
  __hip_bfloat16 h = __float2bfloat16(f);   // RNE; pairs fuse to v_cvt_pk_bf16_f32
  return __builtin_bit_cast(unsigned short, h);
}
static __device__ __forceinline__ float bf2f(unsigned short s) {
  unsigned u = ((unsigned)s) << 16;
  return __builtin_bit_cast(float, u);
}

// ---- prep: head init + W2 -> bf16 B-fragments ----
// frag fi = s*3+t (s=k-step 0..7, t=n-tile 0..2); entry (fi,lane,j):
//   k_global = s*32 + (lane>>4)*8 + j, n = t*16 + (lane&15)
//   W2r[k][n] = W2[kk*768 + t*256 + c*16 + h], kk=k>>4, c=k&15, h=lane&15
__global__ __launch_bounds__(256)
void prep_kernel(const float* __restrict__ W2, unsigned short* __restrict__ w2f,
                 int* __restrict__ head, int N) {
  int gid = blockIdx.x * 256 + threadIdx.x;
  if (gid < N) head[gid] = -1;
  if (gid < 24 * 64) {
    int fi = gid >> 6, lane = gid & 63;
    int s = fi / 3, t = fi - 3 * s;
    int h = lane & 15, kq = lane >> 4;
    short8 pack;
    #pragma unroll
    for (int j = 0; j < 8; ++j) {
      int kg = s * 32 + kq * 8 + j;
      int kk = kg >> 4, c = kg & 15;
      pack[j] = (short)f2bf(W2[kk * 768 + t * 256 + c * 16 + h]);
    }
    *(short8*)&w2f[(size_t)gid * 8] = pack;
  }
}

// ---- K1: per-edge features + compaction + MFMA GEMM + factored-message write ----
__global__ __launch_bounds__(256, 3)
void interact_kernel(const float* __restrict__ xfeat,
                     const float* __restrict__ coords,
                     const int* __restrict__ eidx,
                     const float* __restrict__ W1g,
                     const unsigned short* __restrict__ w2f,
                     unsigned short* __restrict__ data,  // [E][72] bf16
                     int* __restrict__ head,             // [N] init -1
                     int* __restrict__ next,             // [E]
                     int E)
{
  __shared__ __align__(16) float W1s[256];
  __shared__ float hsS[256 * 20];                        // stride 20 f32 (80B)
  __shared__ __align__(16) unsigned short xsS[256 * 24]; // stride 24 ush (48B)
  __shared__ int eS[256];
  __shared__ int wsum[4];

  const int tid  = threadIdx.x;
  const int lane = tid & 63, wid = tid >> 6;
  W1s[tid] = W1g[tid];

  const int e = blockIdx.x * 256 + tid;
  bool act = false;
  int src = 0, dst = 0;
  float rx = 0.f, ry = 0.f, rz = 0.f, d2 = 0.f;
  if (e < E) {
    src = eidx[e]; dst = eidx[E + e];
    rx = coords[3*src]   - coords[3*dst];
    ry = coords[3*src+1] - coords[3*dst+1];
    rz = coords[3*src+2] - coords[3*dst+2];
    d2 = rx*rx + ry*ry + rz*rz;
    act = (d2 > 0.0f) && (d2 < 36.0f);
  }
  // EARLY xfeat issue: depends only on src (0 for edge-OOB lanes -> valid row);
  // latency hides under ballot + bessel instead of stalling the xsS write.
  const float4 xv0 = *(const float4*)&xfeat[src*16 + 0];
  const float4 xv1 = *(const float4*)&xfeat[src*16 + 4];
  const float4 xv2 = *(const float4*)&xfeat[src*16 + 8];
  const float4 xv3 = *(const float4*)&xfeat[src*16 + 12];

  unsigned long long bm = __ballot(act);
  int pfx = __popcll(bm & ((1ull << lane) - 1ull));
  if (lane == 0) wsum[wid] = __popcll(bm);
  __syncthreads();                                   // covers W1s + wsum
  int base = 0;
  #pragma unroll
  for (int w = 0; w < 4; ++w) base += (w < wid) ? wsum[w] : 0;
  const int total = wsum[0] + wsum[1] + wsum[2] + wsum[3];
  const int cpos = base + pfx;

  if (act) {
    float dd  = sqrtf(d2);
    float inv = 1.0f / dd;
    float x = rx*inv, y = ry*inv, z = rz*inv;
    const float A1 = 0.48860251190291992f;  // sqrt(3)/sqrt(4pi)
    const float A2 = 1.09254843059207907f;  // sqrt(15)/sqrt(4pi)
    const float A3 = 0.63078313050504001f;  // sqrt(5)/sqrt(4pi)
    unsigned short* dr = data + (size_t)e * DSTRIDE;
    short8 ys;
    ys[0] = (short)f2bf(A1*x);   ys[1] = (short)f2bf(A1*y);  ys[2] = (short)f2bf(A1*z);
    ys[3] = (short)f2bf(A2*x*z); ys[4] = (short)f2bf(A2*x*y);
    ys[5] = (short)f2bf(A3*(y*y - 0.5f*(x*x + z*z)));
    ys[6] = (short)f2bf(A2*y*z); ys[7] = (short)f2bf(0.5f*A2*(z*z - x*x));
    *(short8*)&dr[64] = ys;
    next[e] = atomicExch(&head[dst], e);   // device-scope

    // bessel -> hidden: h[j] = gain*silu( (eb@W1)[j]/4 ), float4 LDS reads
    float theta = 0.52359877559829887f * dd;   // pi/6 * d
    float s1 = __sinf(theta), c1 = __cosf(theta);
    float snm = 0.0f, sn = s1;
    float4 hbv[4];
    #pragma unroll
    for (int q = 0; q < 4; ++q) hbv[q] = make_float4(0.f, 0.f, 0.f, 0.f);
    #pragma unroll
    for (int k = 0; k < 16; ++k) {
      #pragma unroll
      for (int q = 0; q < 4; ++q) {
        const float4 w = *((const float4*)&W1s[k*16 + q*4]);
        hbv[q].x = fmaf(sn, w.x, hbv[q].x);
        hbv[q].y = fmaf(sn, w.y, hbv[q].y);
        hbv[q].z = fmaf(sn, w.z, hbv[q].z);
        hbv[q].w = fmaf(sn, w.w, hbv[q].w);
      }
      float sp = 2.0f*c1*sn - snm;
      snm = sn; sn = sp;
    }
    const float scale1 = 2.30940107675850305f * inv * 0.25f;
    float* hrow = &hsS[cpos * 20];
    #pragma unroll
    for (int q = 0; q < 4; ++q) {
      float b[4] = {hbv[q].x, hbv[q].y, hbv[q].z, hbv[q].w};
      #pragma unroll
      for (int r = 0; r < 4; ++r) {
        float p = b[r] * scale1;
        hrow[q*4 + r] = 1.679177f * p / (1.0f + __expf(-p));
      }
    }
    unsigned short* xrow = &xsS[cpos * 24];
    xrow[ 0] = f2bf(xv0.x); xrow[ 1] = f2bf(xv0.y); xrow[ 2] = f2bf(xv0.z); xrow[ 3] = f2bf(xv0.w);
    xrow[ 4] = f2bf(xv1.x); xrow[ 5] = f2bf(xv1.y); xrow[ 6] = f2bf(xv1.z); xrow[ 7] = f2bf(xv1.w);
    xrow[ 8] = f2bf(xv2.x); xrow[ 9] = f2bf(xv2.y); xrow[10] = f2bf(xv2.z); xrow[11] = f2bf(xv2.w);
    xrow[12] = f2bf(xv3.x); xrow[13] = f2bf(xv3.y); xrow[14] = f2bf(xv3.z); xrow[15] = f2bf(xv3.w);
    eS[cpos] = e;
  }
  const int padded = (total + 15) & ~15;
  if (tid >= total && tid < padded) {       // zero pad rows
    #pragma unroll
    for (int j = 0; j < 16; ++j) hsS[tid*20 + j] = 0.0f;
    #pragma unroll
    for (int j = 0; j < 16; ++j) xsS[tid*24 + j] = 0;
  }
  __syncthreads();

  // ---- MFMA GEMM [padded,256] x [256,48] ----
  short8 bfr[8][3];
  #pragma unroll
  for (int s = 0; s < 8; ++s)
    #pragma unroll
    for (int t = 0; t < 3; ++t)
      bfr[s][t] = *(const short8*)&w2f[(size_t)((s*3 + t)*64 + lane) * 8];

  const int ngroups = padded >> 4;
  const int ma = lane & 15, kq = lane >> 4;
  const int c0 = (kq & 1) * 8;
  for (int g = wid; g < ngroups; g += 4) {
    const int cidx = g*16 + ma;
    const float* hrow = &hsS[cidx * 20];
    const unsigned short* xrow = &xsS[cidx * 24];
    float xsf[8];
    #pragma unroll
    for (int j = 0; j < 8; ++j) xsf[j] = bf2f(xrow[c0 + j]);

    f32x4 acc0 = {0,0,0,0}, acc1 = {0,0,0,0}, acc2 = {0,0,0,0};
    #pragma unroll
    for (int s = 0; s < 8; ++s) {
      const float hk = hrow[2*s + (kq >> 1)];
      short8 a;
      #pragma unroll
      for (int j = 0; j < 8; ++j) a[j] = (short)f2bf(hk * xsf[j]);
      acc0 = __builtin_amdgcn_mfma_f32_16x16x32_bf16(a, bfr[s][0], acc0, 0, 0, 0);
      acc1 = __builtin_amdgcn_mfma_f32_16x16x32_bf16(a, bfr[s][1], acc1, 0, 0, 0);
      acc2 = __builtin_amdgcn_mfma_f32_16x16x32_bf16(a, bfr[s][2], acc2, 0, 0, 0);
    }
    // D layout: row = kq*4 + r, col = lane&15  (m89-verified)
    const float sc = 0.00390625f;  // 1/256
    #pragma unroll
    for (int r = 0; r < 4; ++r) {
      const int cr = g*16 + kq*4 + r;
      if (cr < total) {
        unsigned short* dr = data + (size_t)eS[cr] * DSTRIDE;
        u16x4 vv;
        vv[0] = f2bf(acc0[r] * sc);
        vv[1] = f2bf(acc1[r] * sc);
        vv[2] = f2bf(acc2[r] * sc);
        vv[3] = 0;
        *(u16x4*)&dr[ma * 4] = vv;
      }
    }
  }
}

// ---- K2: gather (16 threads per node walk the dst list) ----
__global__ __launch_bounds__(256)
void gather_kernel(const unsigned short* __restrict__ data,
                   const int* __restrict__ head,
                   const int* __restrict__ next,
                   float* __restrict__ out, int N)
{
  int gid = blockIdx.x * 256 + threadIdx.x;
  int node = gid >> 4, h = gid & 15;
  if (node >= N) return;

  float a0 = 0.f;
  float a10 = 0.f, a11 = 0.f, a12 = 0.f;
  float a20 = 0.f, a21 = 0.f, a22 = 0.f, a23 = 0.f, a24 = 0.f;

  int p = head[node];
  while (p >= 0) {
    const unsigned short* dr = data + (size_t)p * DSTRIDE;
    int pn = next[p];
    u16x4 vv = *(const u16x4*)&dr[h * 4];
    short8 yv = *(const short8*)&dr[64];
    float v0 = bf2f(vv[0]), v1 = bf2f(vv[1]), v2 = bf2f(vv[2]);
    a0  += v0;
    a10 = fmaf(v1, bf2f((unsigned short)yv[0]), a10);
    a11 = fmaf(v1, bf2f((unsigned short)yv[1]), a11);
    a12 = fmaf(v1, bf2f((unsigned short)yv[2]), a12);
    a20 = fmaf(v2, bf2f((unsigned short)yv[3]), a20);
    a21 = fmaf(v2, bf2f((unsigned short)yv[4]), a21);
    a22 = fmaf(v2, bf2f((unsigned short)yv[5]), a22);
    a23 = fmaf(v2, bf2f((unsigned short)yv[6]), a23);
    a24 = fmaf(v2, bf2f((unsigned short)yv[7]), a24);
    p = pn;
  }

  float* o = out + (size_t)node * 144;
  o[h] = a0 * 0.28209479177387814f;   // Y0 constant folded here
  o[16 + h*3 + 0] = a10;
  o[16 + h*3 + 1] = a11;
  o[16 + h*3 + 2] = a12;
  o[64 + h*5 + 0] = a20;
  o[64 + h*5 + 1] = a21;
  o[64 + h*5 + 2] = a22;
  o[64 + h*5 + 3] = a23;
  o[64 + h*5 + 4] = a24;
}

extern "C" void kernel_launch(void* const* d_in, const int* in_sizes, int n_in,
                              void* d_out, int out_size, void* d_ws, size_t ws_size,
                              hipStream_t stream) {
  const float* xfeat  = (const float*)d_in[0];
  const float* coords = (const float*)d_in[1];
  const int*   eidx   = (const int*)d_in[2];
  const float* W1     = (const float*)d_in[3];
  const float* W2     = (const float*)d_in[4];
  float* out = (float*)d_out;

  const int E = in_sizes[2] / 2;
  const int N = out_size / 144;

  // ws layout (all 16B-aligned): data bf16[E][72] | head[N pad4] | next[E] | w2f[12288 ush]
  char* ws = (char*)d_ws;
  size_t off_head = (size_t)E * DSTRIDE * sizeof(unsigned short);
  size_t off_next = off_head + (size_t)((N + 3) & ~3) * sizeof(int);
  size_t off_w2f  = off_next + (size_t)E * sizeof(int);
  unsigned short* data = (unsigned short*)ws;
  int* head = (int*)(ws + off_head);
  int* next = (int*)(ws + off_next);
  unsigned short* w2f = (unsigned short*)(ws + off_w2f);

  int pblk = (N + 255) / 256;
  if (pblk < 6) pblk = 6;
  prep_kernel<<<pblk, 256, 0, stream>>>(W2, w2f, head, N);
  interact_kernel<<<(E + 255) / 256, 256, 0, stream>>>(xfeat, coords, eidx, W1,
                                                       w2f, data, head, next, E);
  gather_kernel<<<(N * 16 + 255) / 256, 256, 0, stream>>>(data, head, next, out, N);
}